// Round 5
// baseline (720.703 us; speedup 1.0000x reference)
//
#include <hip/hip_runtime.h>
#include <hip/hip_bf16.h>

// Problem constants (ChainGraphDQN)
#define NN 200000      // nodes
#define FIN 128        // in features
#define NE 3200000     // edges
#define NG 4096        // graphs
#define HC 16          // GCN out channels
#define D1 64          // MLP hidden
#define NM 12          // heads
#define NA 8           // actions
#define NBLK 782       // ceil(NN/256)

// Two-level binned edge layout, window-partitioned:
//   level 1: 49 coarse groups (dst>>12), contiguous lists
//   level 2: (fine bin of 64 dst nodes) x (src window) sub-lists
#define BSHIFT 6
#define NBIN 3125                  // NN/64 exactly
#define NGRP 49                    // ceil(NN/4096)
#define CAP1 67584                 // per-group capacity; mean 65536, +8 sigma
#define CH1 16384                  // edges per level-1 block
#define NB1 196                    // ceil(NE/CH1)
#define CH2 8192                   // entries per level-2 block
#define CHK2 9                     // chunks per group = ceil(CAP1/CH2)
#define WNB 6                      // src windows
#define WW 33344                   // window width in nodes (2.13 MB of g_h)
#define CAPW 256                   // per (bin,window) capacity; mean 171, +6.5 sigma

// Scratch in module __device__ globals.
__device__ float    g_h[NN * HC];                        // 12.8 MB, holds h*dinv
__device__ unsigned g_mid[(size_t)NGRP * CAP1];          // 13.2 MB coarse lists
__device__ unsigned g_bucket[(size_t)NBIN * WNB * CAPW]; // 19.2 MB fine lists
__device__ float    g_agg[NN * HC];                      // 12.8 MB partial aggregate
__device__ int      g_scnt1[NGRP];
__device__ int      g_scnt2[NBIN * WNB];
__device__ int      g_degi[NN];
__device__ float    g_dinv[NN];
__device__ float    g_pooled[NG * HC];
__device__ float    g_cnt[NG];

__device__ __forceinline__ void atomAddF(float* p, float v) {
    unsafeAtomicAdd(p, v);
}

// ---------------- zero the accumulators -------------------------------------
__global__ __launch_bounds__(256) void k_zero() {
    int i = blockIdx.x * 256 + threadIdx.x;
    if (i < NN) g_degi[i] = 0;
    if (i < NGRP) g_scnt1[i] = 0;
    if (i < NBIN * WNB) g_scnt2[i] = 0;
    if (i < NG * HC) g_pooled[i] = 0.f;
    if (i < NG) g_cnt[i] = 0.f;
}

// ---------------- level-1 sort: edges -> 49 coarse dst groups ---------------
// 49 keys => fragments of ~334 edges (1.3 KB): stores are line-dense and
// wave-coalesced. Also fuses the degree count. Entry packs src(18) | dst&4095.
__global__ __launch_bounds__(1024) void k_bin1(const int* __restrict__ ei) {
    __shared__ int s_hist[NGRP];
    __shared__ int s_pref[NGRP];
    __shared__ int s_gbase[NGRP];
    __shared__ unsigned short s_perm[CH1];   // 32 KB
    int t = threadIdx.x;
    int e0 = blockIdx.x * CH1;
    int cnt = NE - e0; if (cnt > CH1) cnt = CH1;

    if (t < NGRP) s_hist[t] = 0;
    __syncthreads();
    for (int i = t; i < cnt; i += 1024) {
        int d = ei[NE + e0 + i];
        atomicAdd(&g_degi[d], 1);
        atomicAdd(&s_hist[d >> 12], 1);
    }
    __syncthreads();
    if (t == 0) {
        int run = 0;
        for (int b = 0; b < NGRP; b++) { s_pref[b] = run; run += s_hist[b]; }
    }
    __syncthreads();
    if (t < NGRP) {
        int c = s_hist[t];
        s_gbase[t] = c ? atomicAdd(&g_scnt1[t], c) : 0;
    }
    __syncthreads();
    if (t < NGRP) s_hist[t] = s_pref[t];     // cursor
    __syncthreads();
    for (int i = t; i < cnt; i += 1024) {
        int d = ei[NE + e0 + i];
        int pos = atomicAdd(&s_hist[d >> 12], 1);
        s_perm[pos] = (unsigned short)i;
    }
    __syncthreads();
    for (int i = t; i < cnt; i += 1024) {
        int idx = s_perm[i];
        int s = ei[e0 + idx];
        int d = ei[NE + e0 + idx];
        int grp = d >> 12;
        int gpos = s_gbase[grp] + (i - s_pref[grp]);
        if (gpos < CAP1)
            g_mid[(size_t)grp * CAP1 + gpos] =
                (unsigned)s | ((unsigned)(d & 4095) << 18);
    }
}

// ---------------- level-2 sort: group chunk -> (fine bin, window) -----------
// 384 keys over 8192 entries => ~21-edge (85 B) fragments: ~1.7x write
// amplification, still wave-coalesced. Output lists are contiguous per
// (bin, window) so k_aggw can stage exactly its window's edges.
__global__ __launch_bounds__(1024) void k_bin2() {
    __shared__ int            s_hist[64 * WNB];
    __shared__ unsigned short s_pref[64 * WNB];
    __shared__ unsigned short s_gbase[64 * WNB];
    __shared__ unsigned short s_perm[CH2];   // 16 KB
    int t = threadIdx.x;
    int g = blockIdx.x / CHK2;
    int ch = blockIdx.x % CHK2;
    int total = g_scnt1[g]; if (total > CAP1) total = CAP1;
    int c0 = ch * CH2;
    if (c0 >= total) return;                 // uniform over block
    int cnt = total - c0; if (cnt > CH2) cnt = CH2;
    const unsigned* src = g_mid + (size_t)g * CAP1 + c0;

    if (t < 64 * WNB) s_hist[t] = 0;
    __syncthreads();
    for (int i = t; i < cnt; i += 1024) {
        unsigned p = src[i];
        int key = (int)((p >> 18) >> 6) * WNB + (int)((p & 0x3FFFFu) / WW);
        atomicAdd(&s_hist[key], 1);
    }
    __syncthreads();
    if (t == 0) {
        int run = 0;
        for (int b = 0; b < 64 * WNB; b++) {
            s_pref[b] = (unsigned short)run; run += s_hist[b];
        }
    }
    __syncthreads();
    if (t < 64 * WNB) {
        int c = s_hist[t];
        int gbin = (g << 6) + t / WNB;
        int w = t % WNB;
        s_gbase[t] = (unsigned short)(c ? atomicAdd(&g_scnt2[gbin * WNB + w], c) : 0);
    }
    __syncthreads();
    if (t < 64 * WNB) s_hist[t] = s_pref[t]; // cursor
    __syncthreads();
    for (int i = t; i < cnt; i += 1024) {
        unsigned p = src[i];
        int key = (int)((p >> 18) >> 6) * WNB + (int)((p & 0x3FFFFu) / WW);
        int pos = atomicAdd(&s_hist[key], 1);
        s_perm[pos] = (unsigned short)i;
    }
    __syncthreads();
    for (int i = t; i < cnt; i += 1024) {
        unsigned p = src[s_perm[i]];
        unsigned ss = p & 0x3FFFFu;
        int d12 = (int)(p >> 18);
        int w = (int)(ss / WW);
        int key = (d12 >> 6) * WNB + w;
        int gbin = (g << 6) + (d12 >> 6);
        int gpos = (int)s_gbase[key] + (i - (int)s_pref[key]);
        if (gpos < CAPW)
            g_bucket[(size_t)(gbin * WNB + w) * CAPW + gpos] =
                ss | ((unsigned)(d12 & 63) << 18);
    }
}

// ---------------- dinv = rsqrt(deg+1) ---------------------------------------
__global__ __launch_bounds__(256) void k_dinv() {
    int i = blockIdx.x * 256 + threadIdx.x;
    if (i < NN) g_dinv[i] = rsqrtf((float)(g_degi[i] + 1));
}

// ---------------- h' = (x @ conv_w) * dinv[row]  (LDS-tiled, coalesced) -----
__global__ __launch_bounds__(256) void k_xw(const float* __restrict__ x,
                                            const float* __restrict__ conv_w) {
    __shared__ float s_w[FIN * HC];      // 8 KB
    __shared__ float s_x[64 * 132];      // 33.8 KB
    int t = threadIdx.x;
    for (int i = t; i < FIN * HC; i += 256) s_w[i] = conv_w[i];
    int base = blockIdx.x * 64;
    for (int idx = t; idx < 64 * FIN; idx += 256) {
        int r = idx >> 7, k = idx & 127;
        s_x[r * 132 + k] = x[(size_t)(base + r) * FIN + k];
    }
    __syncthreads();
    int c = t & 15, rg = t >> 4;
    float acc[4] = {0.f, 0.f, 0.f, 0.f};
    for (int k = 0; k < FIN; k++) {
        float w = s_w[k * HC + c];
#pragma unroll
        for (int q = 0; q < 4; q++)
            acc[q] = fmaf(s_x[(rg + 16 * q) * 132 + k], w, acc[q]);
    }
#pragma unroll
    for (int q = 0; q < 4; q++) {
        int row = base + rg + 16 * q;
        g_h[(size_t)row * HC + c] = acc[q] * g_dinv[row];
    }
}

// ---------------- windowed aggregate (6 launches) ---------------------------
// Launch w processes ONLY edges with src in window w (a 2.13 MB slice of g_h):
// every block chip-wide gathers from the same slice => per-XCD L2 holds it,
// gathers hit L2 instead of the ~740 GB/s random-64B-line memory ceiling.
// Partial sums round-trip through g_agg (coalesced stripes, block-exclusive).
// MODE: 0=first (agg starts zero), 1=middle, 2=last (fused relu+mean-pool).
template <int MODE>
__global__ __launch_bounds__(256) void k_aggw(int w,
                                              const float* __restrict__ conv_b,
                                              const int* __restrict__ batch) {
    __shared__ float s_agg[64 * HC];     // 4 KB
    __shared__ unsigned s_lst[CAPW];     // 1 KB
    __shared__ float s_pool[16 * 16];
    __shared__ int s_cnt16[16];
    __shared__ int s_len;
    __shared__ int s_b0;
    int t = threadIdx.x;
    int bk = blockIdx.x;
    int base = bk << BSHIFT;

    if (MODE == 0) {
        for (int i = t; i < 64 * HC; i += 256) s_agg[i] = 0.f;
    } else {
        for (int i = t; i < 64 * HC; i += 256) s_agg[i] = g_agg[bk * 1024 + i];
    }
    if (t == 0) {
        int l = g_scnt2[bk * WNB + w];
        s_len = l < CAPW ? l : CAPW;
        if (MODE == 2) s_b0 = batch[base];
    }
    if (MODE == 2) {
        s_pool[t] = 0.f;
        if (t < 16) s_cnt16[t] = 0;
    }
    __syncthreads();

    int len = s_len;
    const unsigned* lst = g_bucket + (size_t)(bk * WNB + w) * CAPW;
    if (t < len) s_lst[t] = lst[t];      // len <= CAPW = 256
    __syncthreads();

    int q = t >> 2, cq = t & 3;          // 4 lanes per edge, float4 each
    for (int j = q; j < len; j += 64) {
        unsigned p = s_lst[j];
        float4 hv = *(const float4*)&g_h[(size_t)(p & 0x3FFFFu) * HC + 4 * cq];
        float* dp = &s_agg[(p >> 18) * HC + 4 * cq];
        atomicAdd(dp + 0, hv.x);
        atomicAdd(dp + 1, hv.y);
        atomicAdd(dp + 2, hv.z);
        atomicAdd(dp + 3, hv.w);
    }
    __syncthreads();

    if (MODE != 2) {
        for (int i = t; i < 64 * HC; i += 256) g_agg[bk * 1024 + i] = s_agg[i];
        return;
    }

    // ---- last window: self-loop + bias + relu + fused mean-pool ----
    int c = t & 15;
#pragma unroll
    for (int qq = 0; qq < 4; qq++) {
        int ln = (t >> 4) + qq * 16;     // local node 0..63
        int node = base + ln;            // NN = 3125*64 exactly
        float di = g_dinv[node];
        float val = di * (s_agg[ln * HC + c] + g_h[(size_t)node * HC + c])
                    + conv_b[c];
        float r = val > 0.f ? val : 0.f;
        int b = batch[node];
        int slot = b - s_b0;
        if (slot < 16) {
            atomicAdd(&s_pool[slot * 16 + c], r);
            if (c == 0) atomicAdd(&s_cnt16[slot], 1);
        } else {                         // astronomically rare
            atomAddF(&g_pooled[(size_t)b * HC + c], r);
            if (c == 0) atomAddF(&g_cnt[b], 1.f);
        }
    }
    __syncthreads();

    int slot2 = t >> 4;
    if (s_cnt16[slot2] > 0)
        atomAddF(&g_pooled[(size_t)(s_b0 + slot2) * HC + c], s_pool[t]);
    if (t < 16 && s_cnt16[t] > 0)
        atomAddF(&g_cnt[s_b0 + t], (float)s_cnt16[t]);
}

// ---------------- MLP + heads (f32 output) ----------------------------------
__global__ __launch_bounds__(256) void k_mlp(const float* __restrict__ w1,
                                             const float* __restrict__ b1,
                                             const float* __restrict__ w2,
                                             const float* __restrict__ b2,
                                             const float* __restrict__ head_w,
                                             const float* __restrict__ head_b,
                                             float* __restrict__ out) {
    __shared__ float s_w1[HC * D1];
    __shared__ float s_b1[D1];
    __shared__ float s_w2[D1 * D1];
    __shared__ float s_b2[D1];
    __shared__ float s_hw[NM * D1 * NA];
    __shared__ float s_hb[NM * NA];
    __shared__ float s_p[4][HC];
    __shared__ float s_g1[4][D1];
    __shared__ float s_g2[4][D1];

    int tid = threadIdx.x;
    for (int i = tid; i < HC * D1; i += 256) s_w1[i] = w1[i];
    for (int i = tid; i < D1; i += 256) { s_b1[i] = b1[i]; s_b2[i] = b2[i]; }
    for (int i = tid; i < D1 * D1; i += 256) s_w2[i] = w2[i];
    for (int i = tid; i < NM * D1 * NA; i += 256) s_hw[i] = head_w[i];
    for (int i = tid; i < NM * NA; i += 256) s_hb[i] = head_b[i];

    int grp = tid >> 6, lane = tid & 63;
    int g = blockIdx.x * 4 + grp;
    if (lane < HC) {
        float cc = g_cnt[g];
        s_p[grp][lane] = g_pooled[g * HC + lane] / fmaxf(cc, 1.0f);
    }
    __syncthreads();
    {
        float a = s_b1[lane];
#pragma unroll
        for (int c = 0; c < HC; c++) a = fmaf(s_p[grp][c], s_w1[c * D1 + lane], a);
        s_g1[grp][lane] = a > 0.f ? a : expm1f(a);
    }
    __syncthreads();
    {
        float a = s_b2[lane];
#pragma unroll
        for (int d = 0; d < D1; d++) a = fmaf(s_g1[grp][d], s_w2[d * D1 + lane], a);
        s_g2[grp][lane] = a > 0.f ? a : expm1f(a);
    }
    __syncthreads();
    for (int idx = lane; idx < NM * NA; idx += 64) {
        int m = idx >> 3, a = idx & 7;
        float v = s_hb[idx];
#pragma unroll
        for (int d = 0; d < D1; d++)
            v = fmaf(s_g2[grp][d], s_hw[m * (D1 * NA) + d * NA + a], v);
        out[(size_t)g * (NM * NA) + idx] = v;
    }
}

extern "C" void kernel_launch(void* const* d_in, const int* in_sizes, int n_in,
                              void* d_out, int out_size, void* d_ws, size_t ws_size,
                              hipStream_t stream) {
    const float* x      = (const float*)d_in[0];
    const int*   ei     = (const int*)d_in[1];
    const int*   batch  = (const int*)d_in[2];
    const float* conv_w = (const float*)d_in[3];
    const float* conv_b = (const float*)d_in[4];
    const float* w1     = (const float*)d_in[5];
    const float* b1     = (const float*)d_in[6];
    const float* w2     = (const float*)d_in[7];
    const float* b2     = (const float*)d_in[8];
    const float* head_w = (const float*)d_in[9];
    const float* head_b = (const float*)d_in[10];
    float* out = (float*)d_out;

    k_zero<<<NBLK, 256, 0, stream>>>();
    k_bin1<<<NB1, 1024, 0, stream>>>(ei);
    k_bin2<<<NGRP * CHK2, 1024, 0, stream>>>();
    k_dinv<<<NBLK, 256, 0, stream>>>();
    k_xw<<<NN / 64, 256, 0, stream>>>(x, conv_w);
    k_aggw<0><<<NBIN, 256, 0, stream>>>(0, conv_b, batch);
    for (int w = 1; w < WNB - 1; w++)
        k_aggw<1><<<NBIN, 256, 0, stream>>>(w, conv_b, batch);
    k_aggw<2><<<NBIN, 256, 0, stream>>>(WNB - 1, conv_b, batch);
    k_mlp<<<NG / 4, 256, 0, stream>>>(w1, b1, w2, b2, head_w, head_b, out);
}